// Round 10
// baseline (349.429 us; speedup 1.0000x reference)
//
#include <hip/hip_runtime.h>
#include <hip/hip_bf16.h>

// Block-sparse FFN via compacted-weight MFMA, v10 (32x32x16 MFMA, LDS-lean).
//   out = gelu(x @ (W1*M1)^T + b1) @ (W2*M2)^T + b2
// Output groups are 32 cols wide (union of 4 mask rows). Slot = one 8-wide
// k-block as a 8k x 32col bf16 B-tile (512 B). Streams per group, padded to
// x16 slots, contiguous in wave order. Main: MR=32 rows/block, NT=768 (12
// waves, 3/SIMD), 148.5 KB LDS. Window = 8 slots = 4 MFMAs (32x32x16); A/B
// 2-deep prefetch. xs/hs use XOR slot-swizzle (slot ^ (row>>3)) -> conflict-
// free b128 A-gathers. Coalesced float4 epilogue via LDS.

typedef __attribute__((ext_vector_type(8))) short short8;
typedef __attribute__((ext_vector_type(16))) float f32x16;
typedef unsigned long long u64;
typedef unsigned short ushort_t;

#define DIM 768
#define FF 3072
#define NF32 96             // FF/32  fc1 groups
#define NG32 24             // DIM/32 fc2 groups
#define NDB 96              // DIM/8
#define NFB 384             // FF/8
#define MR 32               // x rows per block
#define NT 768              // threads (12 waves)
#define XP 776              // xs pitch (bf16 elems), 1552 B (388 dw % 32 = 4)
#define HP 1544             // hs pitch (bf16 elems), 3088 B (772 dw % 32 = 4)

#define S1CAP (NF32 * 96 + 32)        // 9248 slots max (+ prefetch margin)
#define S2CAP (48 * 192 + 32)         // 9248
#define W1S_TOT (S1CAP * 256)
#define W2S_TOT (S2CAP * 256)

#define MFMA32 __builtin_amdgcn_mfma_f32_32x32x16_bf16

__device__ __forceinline__ float gelu_fast(float v) {
    // x * sigmoid(1.5957691x + 0.07135548x^3) via exp2
    float t2 = v * fmaf(v * v, -0.10295667f, -2.30235629f);
    return v / (1.0f + exp2f(t2));
}
__device__ __forceinline__ ushort_t f2bs(float f) {
    union { __hip_bfloat16 h; ushort_t u; } cv;
    cv.h = __float2bfloat16(f);
    return cv.u;
}

// ---------------- prep 1: per-group padded counts ----------------
__global__ __launch_bounds__(64)
void prep_count(const int* __restrict__ mask1, const int* __restrict__ mask2,
                int* __restrict__ off1, int* __restrict__ off2)
{
    const int l = threadIdx.x;
    const int g = blockIdx.x;
    if (g < NF32) {                       // fc1 group: 4 mask1 rows
        const int* r0 = mask1 + (4 * g) * NDB;
        bool ua = (r0[l] | r0[NDB + l] | r0[2 * NDB + l] | r0[3 * NDB + l]) != 0;
        u64 ba = __ballot(ua);
        bool ub = (l < 32) &&
            ((r0[64 + l] | r0[NDB + 64 + l] | r0[2 * NDB + 64 + l] | r0[3 * NDB + 64 + l]) != 0);
        u64 bb = __ballot(ub);
        if (l == 0) {
            int cnt = __popcll(ba) + __popcll(bb);
            off1[g + 1] = (cnt + 15) & ~15;
        }
    } else {                              // fc2 group: 4 mask2 rows, 2 chunks
        const int G = g - NF32;
        const int* r0 = mask2 + (4 * G) * NFB;
        int c0 = 0, c1 = 0;
        #pragma unroll
        for (int p = 0; p < 6; ++p) {
            int fb = p * 64 + l;
            u64 b = __ballot((r0[fb] | r0[NFB + fb] | r0[2 * NFB + fb] | r0[3 * NFB + fb]) != 0);
            if (p < 3) c0 += __popcll(b); else c1 += __popcll(b);
        }
        if (l == 0) {
            off2[0 * NG32 + G + 1] = (c0 + 15) & ~15;
            off2[1 * NG32 + G + 1] = (c1 + 15) & ~15;
        }
    }
}

// ---------------- prep 2: serial scans + zero idx tails ----------------
__global__ __launch_bounds__(64)
void prep_scan(int* __restrict__ off1, int* __restrict__ off2,
               ushort_t* __restrict__ idx1s, ushort_t* __restrict__ idx2s)
{
    if (threadIdx.x == 0) {
        off1[0] = 0;
        for (int i = 0; i < NF32; ++i) off1[i + 1] += off1[i];
        int e = off1[NF32];
        for (int i = 0; i < 32; ++i) idx1s[e + i] = 0;
    } else if (threadIdx.x == 1) {
        off2[0] = 0;
        for (int i = 0; i < 2 * NG32; ++i) off2[i + 1] += off2[i];
        int e = off2[2 * NG32];
        for (int i = 0; i < 32; ++i) idx2s[e + i] = 0;
    }
}

// ---------------- prep 3: gather weights into B-tile streams ----------------
// Slot layout (256 elems): elem = slot*256 + col*8 + j  (col 0..31, j 0..7)
__global__ __launch_bounds__(256)
void prep_gather(const float* __restrict__ W1, const float* __restrict__ W2,
                 const int* __restrict__ mask1, const int* __restrict__ mask2,
                 const int* __restrict__ off1, const int* __restrict__ off2,
                 __hip_bfloat16* __restrict__ w1s, __hip_bfloat16* __restrict__ w2s,
                 ushort_t* __restrict__ idx1s, ushort_t* __restrict__ idx2s)
{
    __shared__ ushort_t sidx[192];
    __shared__ int sc[1];
    const int tid = threadIdx.x;
    const int l = tid & 63;
    const int g = blockIdx.x;

    if (g < NF32) {                       // ---- fc1 group F ----
        const int F = g;
        const int* r0 = mask1 + (4 * F) * NDB;
        if (tid < 64) {
            bool ua = (r0[l] | r0[NDB + l] | r0[2 * NDB + l] | r0[3 * NDB + l]) != 0;
            u64 ba = __ballot(ua);
            bool ub = (l < 32) &&
                ((r0[64 + l] | r0[NDB + 64 + l] | r0[2 * NDB + 64 + l] | r0[3 * NDB + 64 + l]) != 0);
            u64 bb = __ballot(ub);
            int ca = __popcll(ba);
            if (ua) sidx[__popcll(ba & ((1ull << l) - 1ull))] = (ushort_t)l;
            if (ub) sidx[ca + __popcll(bb & ((1ull << l) - 1ull))] = (ushort_t)(64 + l);
            int cnt = ca + __popcll(bb);
            if (l == 0) {
                sc[0] = cnt;
                int cntp = (cnt + 15) & ~15;
                for (int i = cnt; i < cntp && i < 192; ++i) sidx[i] = 0;
            }
        }
        __syncthreads();
        const int cnt = sc[0];
        const int base = off1[F];
        const int cntp = off1[F + 1] - base;
        if (tid < cntp) idx1s[base + tid] = sidx[tid];
        for (int e = tid; e < cntp * 256; e += 256) {
            int slot = e >> 8, c = (e >> 3) & 31, j = e & 7;
            int db = sidx[slot];
            float w = 0.f;
            if (slot < cnt && mask1[(4 * F + (c >> 3)) * NDB + db])
                w = W1[(long)(F * 32 + c) * DIM + db * 8 + j];
            w1s[(long)(base + slot) * 256 + c * 8 + j] = __float2bfloat16(w);
        }
    } else {                              // ---- fc2 (chunk, G) ----
        const int gi = g - NF32;
        const int c = gi / NG32;
        const int G = gi % NG32;
        const int* r0 = mask2 + (4 * G) * NFB;
        if (tid < 64) {
            u64 b[3]; int pc[3];
            #pragma unroll
            for (int p = 0; p < 3; ++p) {
                int fb = c * 192 + p * 64 + l;
                b[p] = __ballot((r0[fb] | r0[NFB + fb] | r0[2 * NFB + fb] | r0[3 * NFB + fb]) != 0);
                pc[p] = __popcll(b[p]);
            }
            int basea = 0;
            #pragma unroll
            for (int p = 0; p < 3; ++p) {
                if ((b[p] >> l) & 1ull)
                    sidx[basea + __popcll(b[p] & ((1ull << l) - 1ull))] = (ushort_t)(p * 64 + l);
                basea += pc[p];
            }
            if (l == 0) {
                int cnt = basea;
                sc[0] = cnt;
                int cntp = (cnt + 15) & ~15;
                for (int i = cnt; i < cntp && i < 192; ++i) sidx[i] = 0;
            }
        }
        __syncthreads();
        const int cnt = sc[0];
        const int base = off2[c * NG32 + G];
        const int cntp = off2[c * NG32 + G + 1] - base;
        if (tid < cntp) idx2s[base + tid] = sidx[tid];
        for (int e = tid; e < cntp * 256; e += 256) {
            int slot = e >> 8, cc = (e >> 3) & 31, j = e & 7;
            int lfb = sidx[slot];                 // chunk-local fb (0..191)
            int fb = c * 192 + lfb;
            float w = 0.f;
            if (slot < cnt && mask2[(4 * G + (cc >> 3)) * NFB + fb])
                w = W2[(long)(G * 32 + cc) * FF + fb * 8 + j];
            w2s[(long)(base + slot) * 256 + cc * 8 + j] = __float2bfloat16(w);
        }
    }
}

// ---------------- main fused kernel ----------------
// Window = 8 slots = 4 MFMAs (32x32x16). MFMA i uses slots 2i+lh; lane l:
// A row = l&31 (XOR-swizzled slot), B col = l&31, k = lh*8+j.
#define PREF(BUF, IP, WP, ARR, ROWOFF)                                  \
    {                                                                   \
        uint4 q = *(const uint4*)(IP);                                  \
        int m0 = (int)((q.x >> hsh) & 0xffffu) ^ rx;                    \
        int m1 = (int)((q.y >> hsh) & 0xffffu) ^ rx;                    \
        int m2 = (int)((q.z >> hsh) & 0xffffu) ^ rx;                    \
        int m3 = (int)((q.w >> hsh) & 0xffffu) ^ rx;                    \
        BUF##a0 = *(const short8*)&ARR[ROWOFF + m0 * 8];                \
        BUF##a1 = *(const short8*)&ARR[ROWOFF + m1 * 8];                \
        BUF##a2 = *(const short8*)&ARR[ROWOFF + m2 * 8];                \
        BUF##a3 = *(const short8*)&ARR[ROWOFF + m3 * 8];                \
        BUF##w0 = *(const short8*)(WP);                                 \
        BUF##w1 = *(const short8*)(WP + 512);                           \
        BUF##w2 = *(const short8*)(WP + 1024);                          \
        BUF##w3 = *(const short8*)(WP + 1536);                          \
    }

#define PAIRSTEP(IP, WP, ARR, ROWOFF)                                   \
    {                                                                   \
        short8 a0 = Aa0, a1 = Aa1, a2 = Aa2, a3 = Aa3;                  \
        short8 w0 = Aw0, w1 = Aw1, w2 = Aw2, w3 = Aw3;                  \
        PREF(A, IP, WP, ARR, ROWOFF)                                    \
        ca = MFMA32(a0, w0, ca, 0, 0, 0);                               \
        ca = MFMA32(a1, w1, ca, 0, 0, 0);                               \
        ca = MFMA32(a2, w2, ca, 0, 0, 0);                               \
        ca = MFMA32(a3, w3, ca, 0, 0, 0);                               \
    }                                                                   \
    {                                                                   \
        short8 a0 = Ba0, a1 = Ba1, a2 = Ba2, a3 = Ba3;                  \
        short8 w0 = Bw0, w1 = Bw1, w2 = Bw2, w3 = Bw3;                  \
        PREF(B, (IP + 8), (WP + 2048), ARR, ROWOFF)                     \
        cb = MFMA32(a0, w0, cb, 0, 0, 0);                               \
        cb = MFMA32(a1, w1, cb, 0, 0, 0);                               \
        cb = MFMA32(a2, w2, cb, 0, 0, 0);                               \
        cb = MFMA32(a3, w3, cb, 0, 0, 0);                               \
    }                                                                   \
    IP += 16; WP += 4096; s += 16;

__global__ __launch_bounds__(NT)
void bsffn_main(const float* __restrict__ x,
                const float* __restrict__ pb1, const float* __restrict__ pb2,
                const ushort_t* __restrict__ w1s, const ushort_t* __restrict__ w2s,
                const ushort_t* __restrict__ idx1s, const ushort_t* __restrict__ idx2s,
                const int* __restrict__ off1, const int* __restrict__ off2,
                float* __restrict__ out)
{
    __shared__ __align__(16) ushort_t xs[MR * XP];   // 49,664 B
    __shared__ __align__(16) ushort_t hs[MR * HP];   // 98,816 B (reused as f32 sacc)

    const int tid = threadIdx.x;
    const int wave = tid >> 6;                 // 0..11
    const int l = tid & 63;
    const int l31 = l & 31;
    const int lh = l >> 5;
    const int rx = l31 >> 3;                   // XOR swizzle key (row>>3)
    const unsigned hsh = (unsigned)(lh << 4);  // idx half-select shift
    const int xrow = l31 * XP;
    const int hrow = l31 * HP;
    const int wlofs = lh * 256 + l31 * 8;      // lane offset in 512-elem k-step
    const long rowBase = (long)blockIdx.x * MR;

    // ---- stage x tile -> bf16 LDS (slot-swizzled) ----
    {
        const float* xr = x + rowBase * DIM;
        #pragma unroll
        for (int i = 0; i < 4; ++i) {
            int e = tid + i * NT;              // 32 rows x 96 col8-groups
            int row = e / 96, c8 = e % 96;
            const float4 v0 = *(const float4*)(xr + row * DIM + c8 * 8);
            const float4 v1 = *(const float4*)(xr + row * DIM + c8 * 8 + 4);
            uint4 wv;
            wv.x = (unsigned)f2bs(v0.x) | ((unsigned)f2bs(v0.y) << 16);
            wv.y = (unsigned)f2bs(v0.z) | ((unsigned)f2bs(v0.w) << 16);
            wv.z = (unsigned)f2bs(v1.x) | ((unsigned)f2bs(v1.y) << 16);
            wv.w = (unsigned)f2bs(v1.z) | ((unsigned)f2bs(v1.w) << 16);
            *(uint4*)&xs[row * XP + ((c8 ^ (row >> 3)) * 8)] = wv;
        }
    }

    f32x16 accA, accB;
    #pragma unroll
    for (int r = 0; r < 16; ++r) { accA[r] = 0.f; accB[r] = 0.f; }

    __syncthreads();

    for (int chunk = 0; chunk < 2; ++chunk) {
        // ---------- fc1: 4 groups per wave, one linear stream ----------
        {
            const int Fbeg = chunk * 48 + wave * 4;
            int s = off1[Fbeg];
            const ushort_t* ip = idx1s + s;
            const ushort_t* wp = w1s + (long)s * 256 + wlofs;
            short8 Aa0, Aa1, Aa2, Aa3, Aw0, Aw1, Aw2, Aw3;
            short8 Ba0, Ba1, Ba2, Ba3, Bw0, Bw1, Bw2, Bw3;
            PREF(A, ip, wp, xs, xrow)
            PREF(B, (ip + 8), (wp + 2048), xs, xrow)
            ip += 16; wp += 4096;
            #pragma unroll 1
            for (int j = 0; j < 4; ++j) {
                const int F = Fbeg + j;
                const int gend = off1[F + 1];
                f32x16 ca, cb;
                #pragma unroll
                for (int r = 0; r < 16; ++r) { ca[r] = 0.f; cb[r] = 0.f; }
                while (s < gend) { PAIRSTEP(ip, wp, xs, xrow) }
                const float bias = pb1[F * 32 + l31];
                const int hc3 = (F - chunk * 48) * 4 + (l31 >> 3);  // h col slot
                const int he7 = l31 & 7;
                #pragma unroll
                for (int r = 0; r < 16; ++r) {
                    // C/D: col=l31, row=(r&3)+8*(r>>2)+4*lh ; rowswz = r>>2
                    int rs = (r & 3) + 8 * (r >> 2) + 4 * lh;
                    float v = gelu_fast(ca[r] + cb[r] + bias);
                    hs[rs * HP + ((hc3 ^ (r >> 2)) << 3) + he7] = f2bs(v);
                }
            }
        }
        __syncthreads();

        // ---------- fc2: 2 groups per wave, persistent acc ----------
        {
            const int Pbeg = chunk * NG32 + wave * 2;
            int s = off2[Pbeg];
            const ushort_t* ip = idx2s + s;
            const ushort_t* wp = w2s + (long)s * 256 + wlofs;
            short8 Aa0, Aa1, Aa2, Aa3, Aw0, Aw1, Aw2, Aw3;
            short8 Ba0, Ba1, Ba2, Ba3, Bw0, Bw1, Bw2, Bw3;
            PREF(A, ip, wp, hs, hrow)
            PREF(B, (ip + 8), (wp + 2048), hs, hrow)
            ip += 16; wp += 4096;
            {   // group 0
                const int gend = off2[Pbeg + 1];
                f32x16 ca = accA, cb;
                #pragma unroll
                for (int r = 0; r < 16; ++r) cb[r] = 0.f;
                while (s < gend) { PAIRSTEP(ip, wp, hs, hrow) }
                #pragma unroll
                for (int r = 0; r < 16; ++r) accA[r] = ca[r] + cb[r];
            }
            {   // group 1
                const int gend = off2[Pbeg + 2];
                f32x16 ca = accB, cb;
                #pragma unroll
                for (int r = 0; r < 16; ++r) cb[r] = 0.f;
                while (s < gend) { PAIRSTEP(ip, wp, hs, hrow) }
                #pragma unroll
                for (int r = 0; r < 16; ++r) accB[r] = ca[r] + cb[r];
            }
        }
        __syncthreads();
    }

    // ---- epilogue: acc -> LDS (f32) -> coalesced float4 stores ----
    float* sacc = (float*)hs;                       // [32][772] = 98,816 B
    {
        const int d0 = (wave * 2) * 32 + l31;
        const int d1 = (wave * 2 + 1) * 32 + l31;
        #pragma unroll
        for (int r = 0; r < 16; ++r) {
            int rs = (r & 3) + 8 * (r >> 2) + 4 * lh;
            sacc[rs * 772 + d0] = accA[r];
            sacc[rs * 772 + d1] = accB[r];
        }
    }
    __syncthreads();
    {
        const float4* pb24 = (const float4*)pb2;
        #pragma unroll
        for (int i = 0; i < 8; ++i) {
            int e = tid + i * NT;                   // 32 rows x 192 float4
            int row = e / 192, c4 = e % 192;
            float4 v = *(const float4*)&sacc[row * 772 + c4 * 4];
            float4 b = pb24[c4];
            v.x += b.x; v.y += b.y; v.z += b.z; v.w += b.w;
            *(float4*)&out[(rowBase + row) * DIM + c4 * 4] = v;
        }
    }
}

extern "C" void kernel_launch(void* const* d_in, const int* in_sizes, int n_in,
                              void* d_out, int out_size, void* d_ws, size_t ws_size,
                              hipStream_t stream) {
    const float* x = (const float*)d_in[0];
    const float* W1 = (const float*)d_in[1];
    const float* b1 = (const float*)d_in[2];
    const float* W2 = (const float*)d_in[3];
    const float* b2 = (const float*)d_in[4];
    const int* mask1 = (const int*)d_in[5];   // [384,96] int32 0/1
    const int* mask2 = (const int*)d_in[6];   // [96,384]
    float* out = (float*)d_out;

    // ws layout: w1s | w2s | idx1s | idx2s | off1[97] | off2[49]  (~9.5 MiB)
    ushort_t* w1s = (ushort_t*)d_ws;
    ushort_t* w2s = w1s + W1S_TOT;
    ushort_t* idx1s = w2s + W2S_TOT;
    ushort_t* idx2s = idx1s + S1CAP;
    int* off1 = (int*)(idx2s + S2CAP);
    int* off2 = off1 + (NF32 + 1);

    prep_count<<<NF32 + NG32, 64, 0, stream>>>(mask1, mask2, off1, off2);
    prep_scan<<<1, 64, 0, stream>>>(off1, off2, idx1s, idx2s);
    prep_gather<<<NF32 + 2 * NG32, 256, 0, stream>>>(
        W1, W2, mask1, mask2, off1, off2,
        (__hip_bfloat16*)w1s, (__hip_bfloat16*)w2s, idx1s, idx2s);

    const int rows = in_sizes[0] / DIM;        // 36928
    const int nblk = rows / MR;                // 1154
    bsffn_main<<<nblk, NT, 0, stream>>>(
        x, b1, b2, w1s, w2s, idx1s, idx2s, off1, off2, out);
}